// Round 6
// baseline (411.657 us; speedup 1.0000x reference)
//
#include <hip/hip_runtime.h>
#include <math.h>

#define N_NODES 100000
#define D_FEAT  256
#define TOP_K   50000
#define NBINS   65536

// Workspace layout (byte offsets):
//         0 : s32     float[N_NODES]   (400,000)  f32 scores (OpenBLAS+numpy emulation)
//   400,000 : ss      float[N_NODES]   (400,000)  bucket-sorted scores
//   800,000 : si      int[N_NODES]     (400,000)  bucket-sorted node ids
// 1,200,000 : hist    int[NBINS]       (262,144)  } zeroed together
// 1,462,144 : member  uchar[N_NODES]   (100,000)  } (362,144 B memset)
// 1,562,144 : offs    int[NBINS+1]     (262,148)
// 1,824,292 : cursor  int[NBINS]       (262,144)
// 2,086,436 : selIdx  int[TOP_K]       (200,000)
// 2,286,436 : selScore float[TOP_K]    (200,000)
// 2,486,436 : eflag   int[1]           (4)        1 if edge_index stored as int64

__device__ __forceinline__ int bucket_of(float s) {
    int b = (int)(s * 65536.0f);
    return min(max(b, 0), NBINS - 1);
}

// numpy SIMD float32 exp (FMA universal-intrinsics path; same constants on
// AVX2 and AVX512 dispatches):
__device__ __forceinline__ float np_expf(float x) {
    float q  = rintf(x * 1.44269504088896341f);
    float xr = fmaf(-q, 0.693359375f, x);
    xr       = fmaf(-q, -2.12194440e-4f, xr);
    float x2 = xr * xr;
    float p  = 1.9875691500E-4f;
    p = fmaf(p, xr, 1.3981999507E-3f);
    p = fmaf(p, xr, 8.3334519073E-3f);
    p = fmaf(p, xr, 4.1665795894E-2f);
    p = fmaf(p, xr, 1.6666665459E-1f);
    p = fmaf(p, xr, 5.0000001201E-1f);
    p = fmaf(p, x2, xr);
    p = p + 1.0f;
    return ldexpf(p, (int)q);   // exact power-of-2 scale
}

// OpenBLAS sgemv_t haswell/zen microkernel, 4-outputs-at-once path:
//   8 mod-8 FMA lane-chains over k (one ymm acc per output, 8 floats/iter)
//   horizontal via vhaddps merge: z = ((a0+a1)+(a2+a3)) + ((a4+a5)+(a6+a7))
// then numpy f32 sigmoid chain: x=-z; t=np_expf(x); u=1+t; s=1/u.
__global__ void score_kernel(const float* __restrict__ h,
                             const float* __restrict__ W,
                             const float* __restrict__ bvec,
                             float* __restrict__ s32,
                             int* __restrict__ hist) {
    __shared__ float rowbuf[4][256];
    __shared__ float wbuf[256];
    int tid  = threadIdx.x;
    int wave = tid >> 6;
    int lane = tid & 63;
    int node = blockIdx.x * 4 + wave;

    float4 v = ((const float4*)(h + (size_t)node * D_FEAT))[lane];
    *((float4*)&rowbuf[wave][lane * 4]) = v;
    wbuf[tid] = W[tid];
    __syncthreads();

    if (lane == 0) {
        const float* r = rowbuf[wave];
        float acc[8];
#pragma unroll
        for (int l = 0; l < 8; ++l) acc[l] = 0.0f;
        for (int i = 0; i < 32; ++i) {
            int base = i * 8;
#pragma unroll
            for (int l = 0; l < 8; ++l)
                acc[l] = fmaf(r[base + l], wbuf[base + l], acc[l]);
        }
        // vhaddps-style adjacent-pairwise horizontal tree
        float s01 = acc[0] + acc[1];
        float s23 = acc[2] + acc[3];
        float s45 = acc[4] + acc[5];
        float s67 = acc[6] + acc[7];
        float z   = (s01 + s23) + (s45 + s67);
        z = z + bvec[0];                   // + b (b == 0 -> no-op)
        float x = -z;
        float t = np_expf(x);
        float u = 1.0f + t;
        float s = 1.0f / u;                // IEEE f32 divide
        s32[node] = s;
        atomicAdd(&hist[bucket_of(s)], 1);
    }
}

// Single-block exclusive scan of NBINS histogram entries.
__global__ void scan_kernel(const int* __restrict__ hist,
                            int* __restrict__ offs,
                            int* __restrict__ cursor) {
    __shared__ int tmp[1024];
    __shared__ int carry;
    int tid = threadIdx.x;
    if (tid == 0) carry = 0;
    __syncthreads();
    for (int tile = 0; tile < NBINS / 1024; ++tile) {
        int i = tile * 1024 + tid;
        int v = hist[i];
        tmp[tid] = v;
        __syncthreads();
        for (int d = 1; d < 1024; d <<= 1) {
            int t = (tid >= d) ? tmp[tid - d] : 0;
            __syncthreads();
            tmp[tid] += t;
            __syncthreads();
        }
        int incl = tmp[tid];
        int excl = incl - v;
        int base = carry;
        int o = base + excl;
        offs[i]   = o;
        cursor[i] = o;
        __syncthreads();
        if (tid == 1023) carry = base + incl;
        __syncthreads();
    }
    if (tid == 0) offs[NBINS] = carry;   // == N_NODES
}

__global__ void scatter_kernel(const float* __restrict__ s32,
                               int* __restrict__ cursor,
                               float* __restrict__ ss,
                               int* __restrict__ si) {
    int i = blockIdx.x * blockDim.x + threadIdx.x;
    if (i >= N_NODES) return;
    float s = s32[i];
    int b = bucket_of(s);
    int pos = atomicAdd(&cursor[b], 1);
    ss[pos] = s;
    si[pos] = i;
}

// One thread per bucket; insertion sort ascending by (s asc, idx desc)
// so reversed (descending) order is (s desc, idx asc) — lax.top_k tie rule.
__global__ void bucket_sort_kernel(const int* __restrict__ offs,
                                   float* __restrict__ ss,
                                   int* __restrict__ si) {
    int b = blockIdx.x * blockDim.x + threadIdx.x;
    if (b >= NBINS) return;
    int s0 = offs[b], e = offs[b + 1];
    for (int i = s0 + 1; i < e; ++i) {
        float ks = ss[i];
        int   ki = si[i];
        int j = i - 1;
        while (j >= s0) {
            float ps = ss[j];
            int   pi = si[j];
            bool gt = (ps > ks) || (ps == ks && pi < ki);
            if (!gt) break;
            ss[j + 1] = ps;
            si[j + 1] = pi;
            --j;
        }
        ss[j + 1] = ks;
        si[j + 1] = ki;
    }
}

__global__ void emit_kernel(const float* __restrict__ ss,
                            const int* __restrict__ si,
                            float* __restrict__ out_ids,
                            int* __restrict__ selIdx,
                            float* __restrict__ selScore,
                            unsigned char* __restrict__ member) {
    int j = blockIdx.x * blockDim.x + threadIdx.x;
    if (j >= TOP_K) return;
    int p = N_NODES - 1 - j;
    int id = si[p];
    selIdx[j]   = id;
    selScore[j] = ss[p];
    out_ids[j]  = (float)id;
    member[id]  = 1;
}

// new_h[j,:] = h[selIdx[j],:] * selScore[j] (f32 multiply)
__global__ void gather_kernel(const float* __restrict__ h,
                              const int* __restrict__ selIdx,
                              const float* __restrict__ selScore,
                              float* __restrict__ out_newh) {
    int tid  = threadIdx.x;
    int row  = blockIdx.x * 4 + (tid >> 6);
    int lane = tid & 63;
    if (row >= TOP_K) return;
    int id  = selIdx[row];
    float s = selScore[row];
    const float4* hv = (const float4*)(h + (size_t)id * D_FEAT);
    float4 v = hv[lane];
    float4 o = make_float4(v.x * s, v.y * s, v.z * s, v.w * s);
    ((float4*)(out_newh + (size_t)row * D_FEAT))[lane] = o;
}

// Detect whether edge_index is stored int64 (every sampled dword pair has
// hi==0, since indices < 1e5) or int32 (odd dwords are random indices).
__global__ void edge_dtype_detect_kernel(const int* __restrict__ ei,
                                         int* __restrict__ eflag) {
    int all64 = 1;
    for (int i = 0; i < 64; ++i)
        if (ei[2 * i + 1] != 0) all64 = 0;
    eflag[0] = all64;
}

__global__ void edge_kernel(const int* __restrict__ ei,
                            const unsigned char* __restrict__ member,
                            const int* __restrict__ eflag,
                            float* __restrict__ out_mask,
                            int E) {
    int i = blockIdx.x * blockDim.x + threadIdx.x;
    if (i >= E) return;
    int s, d;
    if (eflag[0]) {              // int64 storage: value in even dword
        s = ei[2 * i];
        d = ei[2 * (E + i)];
    } else {                     // int32 storage
        s = ei[i];
        d = ei[E + i];
    }
    bool ok = ((unsigned)s < (unsigned)N_NODES) &&
              ((unsigned)d < (unsigned)N_NODES) &&
              member[s] && member[d];
    out_mask[i] = ok ? 1.0f : 0.0f;
}

extern "C" void kernel_launch(void* const* d_in, const int* in_sizes, int n_in,
                              void* d_out, int out_size, void* d_ws, size_t ws_size,
                              hipStream_t stream) {
    const float* h  = (const float*)d_in[0];
    const float* W  = (const float*)d_in[1];
    const float* bv = (const float*)d_in[2];
    const int*   ei = (const int*)d_in[3];
    const int E = in_sizes[3] / 2;

    char* ws = (char*)d_ws;
    float*         s32      = (float*)(ws + 0);
    float*         ss       = (float*)(ws + 400000);
    int*           si       = (int*)(ws + 800000);
    int*           hist     = (int*)(ws + 1200000);
    unsigned char* member   = (unsigned char*)(ws + 1462144);
    int*           offs     = (int*)(ws + 1562144);
    int*           cursor   = (int*)(ws + 1824292);
    int*           selIdx   = (int*)(ws + 2086436);
    float*         selScore = (float*)(ws + 2286436);
    int*           eflag    = (int*)(ws + 2486436);

    float* out      = (float*)d_out;
    float* out_newh = out;                                  // TOP_K * D_FEAT
    float* out_ids  = out + (size_t)TOP_K * D_FEAT;         // TOP_K
    float* out_mask = out + (size_t)TOP_K * D_FEAT + TOP_K; // E

    hipMemsetAsync(ws + 1200000, 0, 362144, stream);        // hist + member

    score_kernel<<<N_NODES / 4, 256, 0, stream>>>(h, W, bv, s32, hist);
    scan_kernel<<<1, 1024, 0, stream>>>(hist, offs, cursor);
    scatter_kernel<<<(N_NODES + 255) / 256, 256, 0, stream>>>(s32, cursor, ss, si);
    bucket_sort_kernel<<<NBINS / 256, 256, 0, stream>>>(offs, ss, si);
    emit_kernel<<<(TOP_K + 255) / 256, 256, 0, stream>>>(ss, si, out_ids, selIdx, selScore, member);
    gather_kernel<<<TOP_K / 4, 256, 0, stream>>>(h, selIdx, selScore, out_newh);
    edge_dtype_detect_kernel<<<1, 1, 0, stream>>>(ei, eflag);
    edge_kernel<<<(E + 255) / 256, 256, 0, stream>>>(ei, member, eflag, out_mask, E);
}

// Round 7
// 271.655 us; speedup vs baseline: 1.5154x; 1.5154x over previous
//
#include <hip/hip_runtime.h>
#include <math.h>

#define N_NODES 100000
#define D_FEAT  256
#define TOP_K   50000
#define NBINS   65536
#define ROWSTRIDE 260   // 256 + 4 pad: bank = (4g + l + 8i) % 32 -> 2-way = free

// Workspace layout (byte offsets):
//         0 : s32     float[N_NODES]   (400,000)  f32 scores (OpenBLAS+numpy emulation)
//   400,000 : ss      float[N_NODES]   (400,000)  bucket-sorted scores
//   800,000 : si      int[N_NODES]     (400,000)  bucket-sorted node ids
// 1,200,000 : hist    int[NBINS]       (262,144)  } zeroed together
// 1,462,144 : member  uchar[N_NODES]   (100,000)  } (362,144 B memset)
// 1,562,144 : offs    int[NBINS+1]     (262,148)
// 1,824,292 : cursor  int[NBINS]       (262,144)
// 2,086,436 : selIdx  int[TOP_K]       (200,000)
// 2,286,436 : selScore float[TOP_K]    (200,000)
// 2,486,436 : eflag   int[1]           (4)

__device__ __forceinline__ int bucket_of(float s) {
    int b = (int)(s * 65536.0f);
    return min(max(b, 0), NBINS - 1);
}

// numpy SIMD float32 exp (FMA universal-intrinsics path) — bit-exact, verified R6.
__device__ __forceinline__ float np_expf(float x) {
    float q  = rintf(x * 1.44269504088896341f);
    float xr = fmaf(-q, 0.693359375f, x);
    xr       = fmaf(-q, -2.12194440e-4f, xr);
    float x2 = xr * xr;
    float p  = 1.9875691500E-4f;
    p = fmaf(p, xr, 1.3981999507E-3f);
    p = fmaf(p, xr, 8.3334519073E-3f);
    p = fmaf(p, xr, 4.1665795894E-2f);
    p = fmaf(p, xr, 1.6666665459E-1f);
    p = fmaf(p, xr, 5.0000001201E-1f);
    p = fmaf(p, x2, xr);
    p = p + 1.0f;
    return ldexpf(p, (int)q);
}

// OpenBLAS sgemv_t emulation, parallelized 8 lanes/node (R6 numerics, bit-exact):
// lane 8g+l runs chain l (k = i*8+l, i=0..31, serial fmaf) for node g of its wave;
// merge via shfl_xor 1,2,4 reproduces ((a0+a1)+(a2+a3))+((a4+a5)+(a6+a7)).
// Block = 256 thr = 4 waves = 32 nodes; rows staged to LDS coalesced.
__global__ void score_kernel(const float* __restrict__ h,
                             const float* __restrict__ W,
                             const float* __restrict__ bvec,
                             float* __restrict__ s32,
                             int* __restrict__ hist) {
    __shared__ float rows[32 * ROWSTRIDE];   // 33,280 B
    __shared__ float wl[256];
    int tid  = threadIdx.x;
    int wave = tid >> 6;
    int lane = tid & 63;
    int g    = lane >> 3;    // node within wave's 8
    int l    = lane & 7;     // chain id

    wl[tid] = W[tid];

    // stage this wave's 8 rows: one float4 per lane per row, coalesced 1KB
    int nodeBase = blockIdx.x * 32 + wave * 8;
#pragma unroll
    for (int r = 0; r < 8; ++r) {
        float4 v = ((const float4*)(h + (size_t)(nodeBase + r) * D_FEAT))[lane];
        *((float4*)&rows[(wave * 8 + r) * ROWSTRIDE + lane * 4]) = v;
    }
    __syncthreads();

    // W chain-slice into registers: wreg[i] = W[i*8 + l] (8-way LDS broadcast, free)
    float wreg[32];
#pragma unroll
    for (int i = 0; i < 32; ++i) wreg[i] = wl[i * 8 + l];

    // serial chain: acc = sum_{i} h[node][i*8+l] * W[i*8+l], strict fmaf order
    const float* myrow = &rows[(wave * 8 + g) * ROWSTRIDE];
    float acc = 0.0f;
#pragma unroll
    for (int i = 0; i < 32; ++i)
        acc = fmaf(myrow[i * 8 + l], wreg[i], acc);

    // vhaddps-style adjacent-pairwise merge tree (lane 8g+0 holds node g's z)
    float b01 = acc + __shfl_xor(acc, 1, 64);
    float b23 = b01 + __shfl_xor(b01, 2, 64);
    float z   = b23 + __shfl_xor(b23, 4, 64);

    z = z + bvec[0];
    float x = -z;
    float t = np_expf(x);
    float u = 1.0f + t;
    float s = 1.0f / u;                // IEEE f32 divide

    if (l == 0) {
        int node = nodeBase + g;
        s32[node] = s;
        atomicAdd(&hist[bucket_of(s)], 1);
    }
}

// Single-block scan, register-serial: 1024 threads x 64 bins each.
// 3 barriers total (vs ~1300 in the Hillis-Steele version).
__global__ void scan_kernel(const int* __restrict__ hist,
                            int* __restrict__ offs,
                            int* __restrict__ cursor) {
    __shared__ int wsum[16];
    int tid  = threadIdx.x;
    int lane = tid & 63;
    int wid  = tid >> 6;
    int base = tid * 64;

    int v[64];
    int tot = 0;
#pragma unroll
    for (int j = 0; j < 64; ++j) v[j] = hist[base + j];
#pragma unroll
    for (int j = 0; j < 64; ++j) { int t = v[j]; v[j] = tot; tot += t; }  // local exclusive

    // wave-inclusive scan of per-thread totals
    int incl = tot;
#pragma unroll
    for (int d = 1; d < 64; d <<= 1) {
        int t = __shfl_up(incl, d, 64);
        if (lane >= d) incl += t;
    }
    if (lane == 63) wsum[wid] = incl;
    __syncthreads();
    if (tid < 16) {
        int wv = wsum[tid];
        int winc = wv;
#pragma unroll
        for (int d = 1; d < 16; d <<= 1) {
            int t = __shfl_up(winc, d, 64);
            if (tid >= d) winc += t;
        }
        wsum[tid] = winc - wv;   // exclusive wave base
    }
    __syncthreads();

    int excl = (incl - tot) + wsum[wid];
#pragma unroll
    for (int j = 0; j < 64; ++j) {
        int o = excl + v[j];
        offs[base + j]   = o;
        cursor[base + j] = o;
    }
    if (tid == 1023) offs[NBINS] = excl + tot;   // == N_NODES
}

__global__ void scatter_kernel(const float* __restrict__ s32,
                               int* __restrict__ cursor,
                               float* __restrict__ ss,
                               int* __restrict__ si) {
    int i = blockIdx.x * blockDim.x + threadIdx.x;
    if (i >= N_NODES) return;
    float s = s32[i];
    int b = bucket_of(s);
    int pos = atomicAdd(&cursor[b], 1);
    ss[pos] = s;
    si[pos] = i;
}

// One thread per bucket; insertion sort ascending by (s asc, idx desc)
// so reversed (descending) order is (s desc, idx asc) — lax.top_k tie rule.
__global__ void bucket_sort_kernel(const int* __restrict__ offs,
                                   float* __restrict__ ss,
                                   int* __restrict__ si) {
    int b = blockIdx.x * blockDim.x + threadIdx.x;
    if (b >= NBINS) return;
    int s0 = offs[b], e = offs[b + 1];
    for (int i = s0 + 1; i < e; ++i) {
        float ks = ss[i];
        int   ki = si[i];
        int j = i - 1;
        while (j >= s0) {
            float ps = ss[j];
            int   pi = si[j];
            bool gt = (ps > ks) || (ps == ks && pi < ki);
            if (!gt) break;
            ss[j + 1] = ps;
            si[j + 1] = pi;
            --j;
        }
        ss[j + 1] = ks;
        si[j + 1] = ki;
    }
}

__global__ void emit_kernel(const float* __restrict__ ss,
                            const int* __restrict__ si,
                            float* __restrict__ out_ids,
                            int* __restrict__ selIdx,
                            float* __restrict__ selScore,
                            unsigned char* __restrict__ member) {
    int j = blockIdx.x * blockDim.x + threadIdx.x;
    if (j >= TOP_K) return;
    int p = N_NODES - 1 - j;
    int id = si[p];
    selIdx[j]   = id;
    selScore[j] = ss[p];
    out_ids[j]  = (float)id;
    member[id]  = 1;
}

// new_h[j,:] = h[selIdx[j],:] * selScore[j]
__global__ void gather_kernel(const float* __restrict__ h,
                              const int* __restrict__ selIdx,
                              const float* __restrict__ selScore,
                              float* __restrict__ out_newh) {
    int tid  = threadIdx.x;
    int row  = blockIdx.x * 4 + (tid >> 6);
    int lane = tid & 63;
    if (row >= TOP_K) return;
    int id  = selIdx[row];
    float s = selScore[row];
    const float4* hv = (const float4*)(h + (size_t)id * D_FEAT);
    float4 v = hv[lane];
    float4 o = make_float4(v.x * s, v.y * s, v.z * s, v.w * s);
    ((float4*)(out_newh + (size_t)row * D_FEAT))[lane] = o;
}

__global__ void edge_dtype_detect_kernel(const int* __restrict__ ei,
                                         int* __restrict__ eflag) {
    int all64 = 1;
    for (int i = 0; i < 64; ++i)
        if (ei[2 * i + 1] != 0) all64 = 0;
    eflag[0] = all64;
}

__global__ void edge_kernel(const int* __restrict__ ei,
                            const unsigned char* __restrict__ member,
                            const int* __restrict__ eflag,
                            float* __restrict__ out_mask,
                            int E) {
    int i = blockIdx.x * blockDim.x + threadIdx.x;
    if (i >= E) return;
    int s, d;
    if (eflag[0]) {              // int64 storage: value in even dword
        s = ei[2 * i];
        d = ei[2 * (E + i)];
    } else {                     // int32 storage
        s = ei[i];
        d = ei[E + i];
    }
    bool ok = ((unsigned)s < (unsigned)N_NODES) &&
              ((unsigned)d < (unsigned)N_NODES) &&
              member[s] && member[d];
    out_mask[i] = ok ? 1.0f : 0.0f;
}

extern "C" void kernel_launch(void* const* d_in, const int* in_sizes, int n_in,
                              void* d_out, int out_size, void* d_ws, size_t ws_size,
                              hipStream_t stream) {
    const float* h  = (const float*)d_in[0];
    const float* W  = (const float*)d_in[1];
    const float* bv = (const float*)d_in[2];
    const int*   ei = (const int*)d_in[3];
    const int E = in_sizes[3] / 2;

    char* ws = (char*)d_ws;
    float*         s32      = (float*)(ws + 0);
    float*         ss       = (float*)(ws + 400000);
    int*           si       = (int*)(ws + 800000);
    int*           hist     = (int*)(ws + 1200000);
    unsigned char* member   = (unsigned char*)(ws + 1462144);
    int*           offs     = (int*)(ws + 1562144);
    int*           cursor   = (int*)(ws + 1824292);
    int*           selIdx   = (int*)(ws + 2086436);
    float*         selScore = (float*)(ws + 2286436);
    int*           eflag    = (int*)(ws + 2486436);

    float* out      = (float*)d_out;
    float* out_newh = out;                                  // TOP_K * D_FEAT
    float* out_ids  = out + (size_t)TOP_K * D_FEAT;         // TOP_K
    float* out_mask = out + (size_t)TOP_K * D_FEAT + TOP_K; // E

    hipMemsetAsync(ws + 1200000, 0, 362144, stream);        // hist + member

    score_kernel<<<N_NODES / 32, 256, 0, stream>>>(h, W, bv, s32, hist);
    scan_kernel<<<1, 1024, 0, stream>>>(hist, offs, cursor);
    scatter_kernel<<<(N_NODES + 255) / 256, 256, 0, stream>>>(s32, cursor, ss, si);
    bucket_sort_kernel<<<NBINS / 256, 256, 0, stream>>>(offs, ss, si);
    emit_kernel<<<(TOP_K + 255) / 256, 256, 0, stream>>>(ss, si, out_ids, selIdx, selScore, member);
    gather_kernel<<<TOP_K / 4, 256, 0, stream>>>(h, selIdx, selScore, out_newh);
    edge_dtype_detect_kernel<<<1, 1, 0, stream>>>(ei, eflag);
    edge_kernel<<<(E + 255) / 256, 256, 0, stream>>>(ei, member, eflag, out_mask, E);
}